// Round 1
// 237.545 us; speedup vs baseline: 1.0828x; 1.0828x over previous
//
#include <hip/hip_runtime.h>

#define BATCH 16384
#define SEQ 512

typedef float f4 __attribute__((ext_vector_type(4)));
typedef _Float16 half8 __attribute__((ext_vector_type(8)));

// Activation inputs pre-scaled into the weights:
//   sigmoid rows (i,f,o): x -log2(e)  -> A=exp2(p), sig = 1/(1+A)
//   tanh row (g):         x -2log2(e) -> B=exp2(p), tanh=(1-B)/(1+B)
#define SIGS (-1.44269504088896f)
#define TNHS (-2.88539008177793f)

union HB { unsigned int u[4]; half8 h; };

__device__ __forceinline__ float bpermf(int addr, float v) {
    return __int_as_float(__builtin_amdgcn_ds_bpermute(addr, __float_as_int(v)));
}
__device__ __forceinline__ unsigned int bpermu(int addr, unsigned int v) {
    return (unsigned int)__builtin_amdgcn_ds_bpermute(addr, (int)v);
}
__device__ __forceinline__ unsigned int h16(float v) {  // fp16 bits (RNE), low half, high zero
    return (unsigned int)__builtin_bit_cast(unsigned short, (_Float16)v);
}
// v_perm_b32 halfword packers: first arg supplies low 16, second supplies high 16.
__device__ __forceinline__ unsigned int lolo(unsigned int a, unsigned int b) {
    return __builtin_amdgcn_perm(b, a, 0x05040100u);   // a.lo | b.lo<<16
}
__device__ __forceinline__ unsigned int lohi(unsigned int a, unsigned int b) {
    return __builtin_amdgcn_perm(b, a, 0x07060100u);   // a.lo | b.hi<<16
}
__device__ __forceinline__ unsigned int hilo(unsigned int a, unsigned int b) {
    return __builtin_amdgcn_perm(b, a, 0x05040302u);   // a.hi | b.lo<<16
}

// Merged-rcp LSTM cell act: 5 exp2 + 2 rcp (was 3 rcp).
//   r = 1/((1+A)(1+B)(1+F)); f = (1+A)(1+B)*r; i*g = (1-B)*(1+F)*r
__device__ __forceinline__ float act1(float Pi, float Pf, float Pg, float Po, float& c) {
    float A = __builtin_amdgcn_exp2f(Pi);
    float F = __builtin_amdgcn_exp2f(Pf);
    float B = __builtin_amdgcn_exp2f(Pg);
    float O = __builtin_amdgcn_exp2f(Po);
    float ab = (1.0f + A) * (1.0f + B);
    float f1 = 1.0f + F;
    float r  = __builtin_amdgcn_rcpf(ab * f1);
    float f  = ab * r;                    // = 1/(1+F)
    float ig = (1.0f - B) * (f1 * r);     // = tanh(g)*sig(i)
    c = fmaf(f, c, ig);
    float pc = fminf(c * TNHS, 60.0f);
    float Ce = __builtin_amdgcn_exp2f(pc);
    float rho = __builtin_amdgcn_rcpf((1.0f + O) * (1.0f + Ce));
    return (1.0f - Ce) * rho;
}

// ws pair layout: ws[8t+2g] = Wc[t*5+g] (g=0..3), ws[8t+2g+1] = Wc[t*5+4].
// Wc = W2@W1 (MLP collapses: no nonlinearity). ws[4096] = cbias.
__global__ __launch_bounds__(256) void collapse_kernel(
    const float* __restrict__ W1, const float* __restrict__ b1,
    const float* __restrict__ W2, const float* __restrict__ b2,
    float* __restrict__ ws)
{
    const int kl = threadIdx.x & 15;
    const int ms = threadIdx.x >> 4;          // 0..15, 32 rows each
    const int k  = blockIdx.x * 16 + kl;      // 160 blocks * 16 = 2560
    const float* w1p = W1 + (size_t)(ms * 32) * 2560 + k;
    const float* w2p = W2 + ms * 32;
    float acc = 0.f;
    #pragma unroll 8
    for (int m = 0; m < 32; ++m) acc = fmaf(w2p[m], w1p[(size_t)m * 2560], acc);
    __shared__ float red[16][17];
    red[ms][kl] = acc;
    __syncthreads();
    if (ms == 0) {
        float s = 0.f;
        #pragma unroll
        for (int r = 0; r < 16; ++r) s += red[r][kl];
        const int t = k / 5, u = k % 5;
        if (u < 4) ws[8 * t + 2 * u] = s;
        else { ws[8*t + 1] = s; ws[8*t + 3] = s; ws[8*t + 5] = s; ws[8*t + 7] = s; }
    }
    if (blockIdx.x == 0) {
        const int t = threadIdx.x;
        float p = fmaf(W2[t], b1[t], W2[t + 256] * b1[t + 256]);
        #pragma unroll
        for (int off = 32; off > 0; off >>= 1) p += __shfl_down(p, off);
        __shared__ float cred[4];
        if ((t & 63) == 0) cred[t >> 6] = p;
        __syncthreads();
        if (t == 0) ws[4096] = cred[0] + cred[1] + cred[2] + cred[3] + b2[0];
    }
}

// MFMA LSTM, restructured round:
//   [hA,h4 acts] -> q-bperms of (ha|h4) -> BL0 -> MFMA-L0
//   [hC act overlaps q latency] -> r-bperms of hc -> BL1 -> MFMA-L1 (C = L0's dBD)
// dB folded into dD via accumulator chaining (disjoint row sets, merged bias cb).
// No lane-masking in rebuild: garbage B halves multiply structurally-zero A columns.
__global__ __launch_bounds__(64)
__attribute__((amdgpu_waves_per_eu(1, 1)))
void lstm_fused_kernel(
    const float* __restrict__ x,
    const float* __restrict__ Wih0, const float* __restrict__ Whh0,
    const float* __restrict__ bih0, const float* __restrict__ bhh0,
    const float* __restrict__ Wih1, const float* __restrict__ Whh1,
    const float* __restrict__ bih1, const float* __restrict__ bhh1,
    const float* __restrict__ ws, float* __restrict__ out)
{
    const int lane = threadIdx.x;
    const int e15  = lane & 15;
    const int g    = lane >> 4;          // k-block / lane group
    const int e    = blockIdx.x * 16 + e15;
    const float sc[4] = {SIGS, SIGS, TNHS, SIGS};

    // ---- A fragments (weights, fp16): lane holds A[m=e15][k=8g+j], j=0..7 ----
    HB aL0a, aL0b, aL1a, aL1b;
    {
        const int m = e15, kb = g * 8;
        {   // L0a: row m -> cell L0u(m>>2), gate (m&3)
            const int u = m >> 2, gi = m & 3, row = gi * 5 + u;
            float w[8];
            #pragma unroll
            for (int j = 0; j < 8; ++j) {
                const int k = kb + j;
                float v = (k == 0) ? Wih0[row] : (k <= 5 ? Whh0[row * 5 + k - 1] : 0.f);
                w[j] = v * sc[gi];
            }
            #pragma unroll
            for (int d = 0; d < 4; ++d) aL0a.u[d] = h16(w[2*d]) | (h16(w[2*d+1]) << 16);
        }
        {   // L0b: rows 4..7 = L0u4, gate (m-4)
            float w[8] = {0,0,0,0,0,0,0,0};
            if (m >= 4 && m < 8) {
                const int gi = m - 4, row = gi * 5 + 4;
                #pragma unroll
                for (int j = 0; j < 8; ++j) {
                    const int k = kb + j;
                    float v = (k == 0) ? Wih0[row] : (k <= 5 ? Whh0[row * 5 + k - 1] : 0.f);
                    w[j] = v * sc[gi];
                }
            }
            #pragma unroll
            for (int d = 0; d < 4; ++d) aL0b.u[d] = h16(w[2*d]) | (h16(w[2*d+1]) << 16);
        }
        {   // L1a: row m -> cell L1u(m>>2), gate (m&3); k0-4=Wih1, k5-9=Whh1
            const int u = m >> 2, gi = m & 3, row = gi * 5 + u;
            float w[8];
            #pragma unroll
            for (int j = 0; j < 8; ++j) {
                const int k = kb + j;
                float v = (k <= 4) ? Wih1[row * 5 + k]
                        : (k <= 9 ? Whh1[row * 5 + k - 5] : 0.f);
                w[j] = v * sc[gi];
            }
            #pragma unroll
            for (int d = 0; d < 4; ++d) aL1a.u[d] = h16(w[2*d]) | (h16(w[2*d+1]) << 16);
        }
        {   // L1b: rows 8..11 = L1u4, gate (m-8)
            float w[8] = {0,0,0,0,0,0,0,0};
            if (m >= 8 && m < 12) {
                const int gi = m - 8, row = gi * 5 + 4;
                #pragma unroll
                for (int j = 0; j < 8; ++j) {
                    const int k = kb + j;
                    float v = (k <= 4) ? Wih1[row * 5 + k]
                            : (k <= 9 ? Whh1[row * 5 + k - 5] : 0.f);
                    w[j] = v * sc[gi];
                }
            }
            #pragma unroll
            for (int d = 0; d < 4; ++d) aL1b.u[d] = h16(w[2*d]) | (h16(w[2*d+1]) << 16);
        }
    }
    // ---- C fragments (biases, fp32): lane reg r -> row 4g+r; cb = merged u4 bias ----
    f4 cL0a, cL1a, cb;
    #pragma unroll
    for (int r = 0; r < 4; ++r) {
        cL0a[r] = (bih0[r*5+g] + bhh0[r*5+g]) * sc[r];
        cL1a[r] = (bih1[r*5+g] + bhh1[r*5+g]) * sc[r];
        cb[r]   = (g == 1) ? (bih0[r*5+4] + bhh0[r*5+4]) * sc[r]
                : (g == 2) ? (bih1[r*5+4] + bhh1[r*5+4]) * sc[r] : 0.f;
    }

    const float* xp = x + (size_t)e * SEQ;
    const bool l16 = lane < 16;
    const int aP1 = (e15 + 16) << 2, aP2 = (e15 + 32) << 2, aP3 = (e15 + 48) << 2;
    const int aP5 = ((l16 ? lane + 16 : lane + 32) & 63) << 2;

    float c0 = 0.f, c1 = 0.f, c4 = 0.f, acc = 0.f, acc4 = 0.f;
    f4 dA, dC, dD;

    // ---- prologue: round 0 (L0 step 0 real; L1 forced to zero state) ----
    {
        HB B0, B1;
        B0.u[0] = h16(xp[0]);  B0.u[1] = B0.u[2] = B0.u[3] = 0u;
        dA = __builtin_amdgcn_mfma_f32_16x16x32_f16(aL0a.h, B0.h, cL0a, 0, 0, 0);
        f4 dBD = __builtin_amdgcn_mfma_f32_16x16x32_f16(aL0b.h, B0.h, cb, 0, 0, 0);
        float hA0 = act1(dA[0], dA[1], dA[2], dA[3], c0);
        float h40 = act1(dBD[0], dBD[1], dBD[2], dBD[3], c4);
        if (g == 2) { h40 = 0.f; c4 = 0.f; }      // h1u4(-1) = 0
        unsigned hx0 = h16(hA0) | (h16(h40) << 16);
        unsigned q1 = bpermu(aP1, hx0), q2 = bpermu(aP2, hx0), q3 = bpermu(aP3, hx0);
        B0.u[0] = lolo(h16(xp[1]), hx0);          // (x(1), h0u0)
        B0.u[1] = lolo(q1, q2);                   // (h0u1, h0u2)
        B0.u[2] = lohi(q3, q1);                   // (h0u3, h0u4)
        B0.u[3] = 0u;
        dA = __builtin_amdgcn_mfma_f32_16x16x32_f16(aL0a.h, B0.h, cL0a, 0, 0, 0);
        f4 nBD = __builtin_amdgcn_mfma_f32_16x16x32_f16(aL0b.h, B0.h, cb, 0, 0, 0);
        B1.u[0] = l16 ? lolo(hx0, q1) : lohi(0u, q2);  // (h0u0,h0u1) | (h1u3=0, h1u4=0)
        B1.u[1] = lolo(q2, q3);                   // (h0u2, h0u3)
        B1.u[2] = hilo(q1, 0u);                   // (h0u4, h1u0=0)
        B1.u[3] = 0u;                             // (h1u1=0, h1u2=0)
        dC = __builtin_amdgcn_mfma_f32_16x16x32_f16(aL1a.h, B1.h, cL1a, 0, 0, 0);
        dD = __builtin_amdgcn_mfma_f32_16x16x32_f16(aL1b.h, B1.h, nBD, 0, 0, 0);
    }

    // prefetch buffers for bodies 1..4: x(2..5), Wc pairs t=0..3
    unsigned xh16[4]; float wM[4], w4b[4];
    #pragma unroll
    for (int u = 0; u < 4; ++u) {
        xh16[u] = h16(xp[2 + u]);
        float2 w = *(const float2*)(ws + 8 * u + 2 * g);
        wM[u] = w.x;  w4b[u] = w.y;
    }

    // body(round m): acts from dA/dC/dD, build B(m+1), issue MFMAs(m+1)
    auto body = [&](unsigned xh_next, float wMu, float w4u) {
        float hAn = act1(dA[0], dA[1], dA[2], dA[3], c0);      // h0u_g (step m)
        float h4n = act1(dD[0], dD[1], dD[2], dD[3], c4);      // g1: h0u4, g2: h1u4
        unsigned hx0 = h16(hAn) | (h16(h4n) << 16);
        unsigned q1 = bpermu(aP1, hx0);   // (h0u1, h0u4)
        unsigned q2 = bpermu(aP2, hx0);   // (h0u2, h1u4)
        unsigned q3 = bpermu(aP3, hx0);   // (h0u3, h4(g3) unused)
        float hCn = act1(dC[0], dC[1], dC[2], dC[3], c1);      // h1u_g (step m-1), hides q
        acc  = fmaf(hCn, wMu, acc);                            // fused MLP head
        acc4 = fmaf(h4n, w4u, acc4);                           // (only g2's is used)
        unsigned hc16 = h16(hCn);
        unsigned ra = bpermu(aP5, hc16);  // <16: h1u1 ; 16-31: h1u3
        unsigned rb = bpermu(aP2, hc16);  // h1u2
        HB B0;
        B0.u[0] = lolo(xh_next, hx0);     // (x, h0u0)
        B0.u[1] = lolo(q1, q2);           // (h0u1, h0u2)
        B0.u[2] = lohi(q3, q1);           // (h0u3, h0u4)
        B0.u[3] = 0u;
        f4 nA  = __builtin_amdgcn_mfma_f32_16x16x32_f16(aL0a.h, B0.h, cL0a, 0, 0, 0);
        f4 nBD = __builtin_amdgcn_mfma_f32_16x16x32_f16(aL0b.h, B0.h, cb, 0, 0, 0);
        HB B1;
        B1.u[0] = l16 ? lolo(hx0, q1)     // (h0u0, h0u1)
                      : lohi(ra, q2);     // lanes16-31: (k8=h1u3, k9=h1u4)
        B1.u[1] = lolo(q2, q3);           // (h0u2, h0u3)
        B1.u[2] = hilo(q1, hc16);         // (h0u4, h1u0)
        B1.u[3] = lolo(ra, rb);           // (h1u1, h1u2)
        dC = __builtin_amdgcn_mfma_f32_16x16x32_f16(aL1a.h, B1.h, cL1a, 0, 0, 0);
        dD = __builtin_amdgcn_mfma_f32_16x16x32_f16(aL1b.h, B1.h, nBD, 0, 0, 0);
        dA = nA;
    };

    for (int m = 1; m < 513; m += 4) {              // bodies 1..512, blocks of 4
        unsigned xhn[4]; float wMn[4], w4n[4];
        #pragma unroll
        for (int u = 0; u < 4; ++u) {
            xhn[u] = h16(xp[min(m + 5 + u, SEQ - 1)]);
            const int t = min(m + 3 + u, SEQ - 1);
            float2 w = *(const float2*)(ws + 8 * t + 2 * g);
            wMn[u] = w.x;  w4n[u] = w.y;
        }
        #pragma unroll
        for (int u = 0; u < 4; ++u) body(xh16[u], wM[u], w4b[u]);
        #pragma unroll
        for (int u = 0; u < 4; ++u) { xh16[u] = xhn[u]; wM[u] = wMn[u]; w4b[u] = w4n[u]; }
    }

    // reduce: element e partials live on lanes e, e+16, e+32(+u4), e+48
    float accT = acc + ((g == 2) ? acc4 : 0.f);
    float t0 = bpermf(e15 << 2, accT);
    float t1 = bpermf((e15 + 16) << 2, accT);
    float t2 = bpermf((e15 + 32) << 2, accT);
    float t3 = bpermf((e15 + 48) << 2, accT);
    if (lane < 16) out[e] = (t0 + t1) + (t2 + t3) + ws[4096];
}

extern "C" void kernel_launch(void* const* d_in, const int* in_sizes, int n_in,
                              void* d_out, int out_size, void* d_ws, size_t ws_size,
                              hipStream_t stream) {
    const float* x    = (const float*)d_in[0];
    const float* Wih0 = (const float*)d_in[1];
    const float* Whh0 = (const float*)d_in[2];
    const float* bih0 = (const float*)d_in[3];
    const float* bhh0 = (const float*)d_in[4];
    const float* Wih1 = (const float*)d_in[5];
    const float* Whh1 = (const float*)d_in[6];
    const float* bih1 = (const float*)d_in[7];
    const float* bhh1 = (const float*)d_in[8];
    const float* W1   = (const float*)d_in[9];
    const float* b1   = (const float*)d_in[10];
    const float* W2   = (const float*)d_in[11];
    const float* b2   = (const float*)d_in[12];
    float* out = (float*)d_out;
    float* ws  = (float*)d_ws;

    collapse_kernel<<<160, 256, 0, stream>>>(W1, b1, W2, b2, ws);
    lstm_fused_kernel<<<BATCH / 16, 64, 0, stream>>>(x, Wih0, Whh0, bih0, bhh0,
                                                     Wih1, Whh1, bih1, bhh1, ws, out);
}

// Round 2
// 212.626 us; speedup vs baseline: 1.2097x; 1.1172x over previous
//
#include <hip/hip_runtime.h>

#define BATCH 16384
#define SEQ 512

typedef float f4 __attribute__((ext_vector_type(4)));
typedef _Float16 half4 __attribute__((ext_vector_type(4)));

// Activation inputs pre-scaled into the weights:
//   sigmoid rows (i,f,o): x -log2(e)  -> A=exp2(p), sig = 1/(1+A)
//   tanh row (g):         x -2log2(e) -> B=exp2(p), tanh=(1-B)/(1+B)
#define SIGS (-1.44269504088896f)
#define TNHS (-2.88539008177793f)

union HB2 { unsigned int u[2]; half4 h; };

__device__ __forceinline__ float bpermf(int addr, float v) {
    return __int_as_float(__builtin_amdgcn_ds_bpermute(addr, __float_as_int(v)));
}
__device__ __forceinline__ unsigned int h16(float v) {  // fp16 bits (RNE), low half
    return (unsigned int)__builtin_bit_cast(unsigned short, (_Float16)v);
}
// v_perm_b32 halfword packer: a.lo | b.lo<<16
__device__ __forceinline__ unsigned int lolo(unsigned int a, unsigned int b) {
    return __builtin_amdgcn_perm(b, a, 0x05040100u);
}

// Triple-merged LSTM cell act: 15 exp2 + 2 rcp for THREE chains (was 15+6).
// Per chain: t=1+A; ab=fma(t,B,t); D=fma(ab,F,ab)  [D=(1+A)(1+B)(1+F)]
// grand r = rcp(D0*D1*D2), per-chain r_i = r * (other two D's).
// Output side same trick on den=(1+O)(1+Ce). pc clamped at 17 (tanh sat.,
// keeps den<=2^25/chain so grand den product stays < 2^80: no overflow).
// Worst-case D<=2^33/chain -> grand <= 2^99 < 2^127: safe.
__device__ __forceinline__ void act3(const f4& dA, const f4& dD, const f4& dC,
                                     float& c0, float& c4, float& c1,
                                     float& hA, float& h4, float& hC) {
    float A0 = __builtin_amdgcn_exp2f(dA[0]), F0 = __builtin_amdgcn_exp2f(dA[1]);
    float B0 = __builtin_amdgcn_exp2f(dA[2]), O0 = __builtin_amdgcn_exp2f(dA[3]);
    float A1 = __builtin_amdgcn_exp2f(dD[0]), F1 = __builtin_amdgcn_exp2f(dD[1]);
    float B1 = __builtin_amdgcn_exp2f(dD[2]), O1 = __builtin_amdgcn_exp2f(dD[3]);
    float A2 = __builtin_amdgcn_exp2f(dC[0]), F2 = __builtin_amdgcn_exp2f(dC[1]);
    float B2 = __builtin_amdgcn_exp2f(dC[2]), O2 = __builtin_amdgcn_exp2f(dC[3]);

    float t0 = 1.0f + A0, t1 = 1.0f + A1, t2 = 1.0f + A2;
    float ab0 = fmaf(t0, B0, t0), ab1 = fmaf(t1, B1, t1), ab2 = fmaf(t2, B2, t2);
    float D0 = fmaf(ab0, F0, ab0), D1 = fmaf(ab1, F1, ab1), D2 = fmaf(ab2, F2, ab2);
    float p01 = D0 * D1, p12 = D1 * D2, p02 = D0 * D2;
    float r = __builtin_amdgcn_rcpf(p01 * D2);
    float r0 = r * p12, r1 = r * p02, r2 = r * p01;

    float bm0 = 1.0f - B0, bm1 = 1.0f - B1, bm2 = 1.0f - B2;
    float w0 = fmaf(bm0, F0, bm0), w1 = fmaf(bm1, F1, bm1), w2 = fmaf(bm2, F2, bm2);
    c0 = fmaf(ab0 * r0, c0, w0 * r0);
    c4 = fmaf(ab1 * r1, c4, w1 * r1);
    c1 = fmaf(ab2 * r2, c1, w2 * r2);

    float pc0 = fminf(c0 * TNHS, 17.0f);
    float pc1 = fminf(c4 * TNHS, 17.0f);
    float pc2 = fminf(c1 * TNHS, 17.0f);
    float Ce0 = __builtin_amdgcn_exp2f(pc0);
    float Ce1 = __builtin_amdgcn_exp2f(pc1);
    float Ce2 = __builtin_amdgcn_exp2f(pc2);
    float o0 = 1.0f + O0, o1 = 1.0f + O1, o2 = 1.0f + O2;
    float e0 = fmaf(o0, Ce0, o0), e1 = fmaf(o1, Ce1, o1), e2 = fmaf(o2, Ce2, o2);
    float q01 = e0 * e1, q12 = e1 * e2, q02 = e0 * e2;
    float rr = __builtin_amdgcn_rcpf(q01 * e2);
    hA = (1.0f - Ce0) * (rr * q12);
    h4 = (1.0f - Ce1) * (rr * q02);
    hC = (1.0f - Ce2) * (rr * q01);
}

// ws pair layout: ws[8t+2g] = Wc[t*5+g] (g=0..3), ws[8t+2g+1] = Wc[t*5+4].
// Wc = W2@W1 (MLP collapses: no nonlinearity). ws[4096] = cbias.
__global__ __launch_bounds__(256) void collapse_kernel(
    const float* __restrict__ W1, const float* __restrict__ b1,
    const float* __restrict__ W2, const float* __restrict__ b2,
    float* __restrict__ ws)
{
    const int kl = threadIdx.x & 15;
    const int ms = threadIdx.x >> 4;          // 0..15, 32 rows each
    const int k  = blockIdx.x * 16 + kl;      // 160 blocks * 16 = 2560
    const float* w1p = W1 + (size_t)(ms * 32) * 2560 + k;
    const float* w2p = W2 + ms * 32;
    float acc = 0.f;
    #pragma unroll 8
    for (int m = 0; m < 32; ++m) acc = fmaf(w2p[m], w1p[(size_t)m * 2560], acc);
    __shared__ float red[16][17];
    red[ms][kl] = acc;
    __syncthreads();
    if (ms == 0) {
        float s = 0.f;
        #pragma unroll
        for (int r = 0; r < 16; ++r) s += red[r][kl];
        const int t = k / 5, u = k % 5;
        if (u < 4) ws[8 * t + 2 * u] = s;
        else { ws[8*t + 1] = s; ws[8*t + 3] = s; ws[8*t + 5] = s; ws[8*t + 7] = s; }
    }
    if (blockIdx.x == 0) {
        const int t = threadIdx.x;
        float p = fmaf(W2[t], b1[t], W2[t + 256] * b1[t + 256]);
        #pragma unroll
        for (int off = 32; off > 0; off >>= 1) p += __shfl_down(p, off);
        __shared__ float cred[4];
        if ((t & 63) == 0) cred[t >> 6] = p;
        __syncthreads();
        if (t == 0) ws[4096] = cred[0] + cred[1] + cred[2] + cred[3] + b2[0];
    }
}

// Bperm-free MFMA LSTM. K-slot layout chosen so every B-fragment half-word is
// produced by the lane that packs it (group c owns cell c; u4 on g1/g2):
//   B0 (K=16, layer0): g0:{k0=h0u0, k1=x}  g1:{k4=h0u1, k5=h0u4}
//                      g2:{k8=h0u2}        g3:{k12=h0u3}
//   B1 (layer1):       g0:{h0u0, h1u0}     g1:{h0u1, h1u1, h0u4}
//                      g2:{h0u2, h1u2, h1u4}  g3:{h0u3, h1u3}
// => B1 = {lolo(hx0,hc16), hx0>>16}; B0 = {g0? lolo(hx0,xh) : hx0, 0}.
// Unused slots hold garbage x structurally-zero A columns (|h|<=1: no Inf).
// mfma_f32_16x16x16f16 (K=16) replaces 16x16x32. dBD->dD accumulator chaining
// merges L0u4 (rows 4-7 -> g1) and L1u4 (rows 8-11 -> g2) into one act chain.
__global__ __launch_bounds__(64)
__attribute__((amdgpu_waves_per_eu(1, 1)))
void lstm_fused_kernel(
    const float* __restrict__ x,
    const float* __restrict__ Wih0, const float* __restrict__ Whh0,
    const float* __restrict__ bih0, const float* __restrict__ bhh0,
    const float* __restrict__ Wih1, const float* __restrict__ Whh1,
    const float* __restrict__ bih1, const float* __restrict__ bhh1,
    const float* __restrict__ ws, float* __restrict__ out)
{
    const int lane = threadIdx.x;
    const int e15  = lane & 15;
    const int g    = lane >> 4;          // k-block / lane group / cell index
    const int e    = blockIdx.x * 16 + e15;
    const float sc[4] = {SIGS, SIGS, TNHS, SIGS};

    // ---- A fragments (weights, fp16): lane holds A[row=e15][k=4g+j], j=0..3 ----
    HB2 aL0a, aL0b, aL1a, aL1b;
    {
        const int m = e15;
        {   // L0a: row m -> cell u=m>>2, gate gi=m&3; cols: k0=Whh0[.][g], k1: g0->x, g1->h0u4
            const int u = m >> 2, gi = m & 3, gr = gi * 5 + u;
            const float s = sc[gi];
            float w0 = Whh0[gr * 5 + g];
            float w1 = (g == 0) ? Wih0[gr] : (g == 1 ? Whh0[gr * 5 + 4] : 0.f);
            aL0a.u[0] = h16(w0 * s) | (h16(w1 * s) << 16);
            aL0a.u[1] = 0u;
        }
        {   // L0b: rows 4..7 = L0u4 gates, same column map
            float w0 = 0.f, w1 = 0.f, s = 0.f;
            if (m >= 4 && m < 8) {
                const int gi = m - 4, gr = gi * 5 + 4;
                s = sc[gi];
                w0 = Whh0[gr * 5 + g];
                w1 = (g == 0) ? Wih0[gr] : (g == 1 ? Whh0[gr * 5 + 4] : 0.f);
            }
            aL0b.u[0] = h16(w0 * s) | (h16(w1 * s) << 16);
            aL0b.u[1] = 0u;
        }
        {   // L1a: row m -> cell u, gate gi; cols: slot0=Wih1[.][g], slot1=Whh1[.][g],
            //      slot2: g1->Wih1[.][4] (h0u4), g2->Whh1[.][4] (h1u4)
            const int u = m >> 2, gi = m & 3, gr = gi * 5 + u;
            const float s = sc[gi];
            float w0 = Wih1[gr * 5 + g];
            float w1 = Whh1[gr * 5 + g];
            float w2 = (g == 1) ? Wih1[gr * 5 + 4] : (g == 2 ? Whh1[gr * 5 + 4] : 0.f);
            aL1a.u[0] = h16(w0 * s) | (h16(w1 * s) << 16);
            aL1a.u[1] = h16(w2 * s);
        }
        {   // L1b: rows 8..11 = L1u4 gates, same column map
            float w0 = 0.f, w1 = 0.f, w2 = 0.f, s = 0.f;
            if (m >= 8 && m < 12) {
                const int gi = m - 8, gr = gi * 5 + 4;
                s = sc[gi];
                w0 = Wih1[gr * 5 + g];
                w1 = Whh1[gr * 5 + g];
                w2 = (g == 1) ? Wih1[gr * 5 + 4] : (g == 2 ? Whh1[gr * 5 + 4] : 0.f);
            }
            aL1b.u[0] = h16(w0 * s) | (h16(w1 * s) << 16);
            aL1b.u[1] = h16(w2 * s);
        }
    }
    // ---- C fragments (biases, fp32): lane reg r -> row 4g+r; cb = merged u4 bias ----
    f4 cL0a, cL1a, cb;
    #pragma unroll
    for (int r = 0; r < 4; ++r) {
        cL0a[r] = (bih0[r*5+g] + bhh0[r*5+g]) * sc[r];
        cL1a[r] = (bih1[r*5+g] + bhh1[r*5+g]) * sc[r];
        cb[r]   = (g == 1) ? (bih0[r*5+4] + bhh0[r*5+4]) * sc[r]
                : (g == 2) ? (bih1[r*5+4] + bhh1[r*5+4]) * sc[r] : 0.f;
    }

    const float* xp = x + (size_t)e * SEQ;
    const bool isg0 = (g == 0), isg2 = (g == 2);

    float c0 = 0.f, c1 = 0.f, c4 = 0.f, acc = 0.f, acc4 = 0.f;
    f4 dA, dC, dD;

    // ---- prologue: step 0 (L0 real; L1 state forced to zero) ----
    {
        unsigned xh0 = h16(xp[0]);
        HB2 b0; b0.u[0] = isg0 ? (xh0 << 16) : 0u; b0.u[1] = 0u;   // k0=h0u0(-1)=0, k1=x(0)
        dA = __builtin_amdgcn_mfma_f32_16x16x16f16(aL0a.h, b0.h, cL0a, 0, 0, 0);
        f4 dBD = __builtin_amdgcn_mfma_f32_16x16x16f16(aL0b.h, b0.h, cb, 0, 0, 0);
        dC = cL1a;     // B1 = 0: layer1 garbage, reset below
        dD = dBD;
        float hA, h4, hC;
        act3(dA, dD, dC, c0, c4, c1, hA, h4, hC);
        if (isg2) { h4 = 0.f; c4 = 0.f; }   // h1u4(-1) = 0
        hC = 0.f; c1 = 0.f;                 // h1(-1) = 0
        unsigned hx0 = h16(hA) | (h16(h4) << 16);
        unsigned xh1 = h16(xp[1]);
        HB2 B0n, B1n;
        B0n.u[0] = isg0 ? lolo(hx0, xh1) : hx0;  B0n.u[1] = 0u;
        B1n.u[0] = hx0 & 0xFFFFu;                B1n.u[1] = hx0 >> 16;   // hc16 = 0
        dA = __builtin_amdgcn_mfma_f32_16x16x16f16(aL0a.h, B0n.h, cL0a, 0, 0, 0);
        f4 nBD = __builtin_amdgcn_mfma_f32_16x16x16f16(aL0b.h, B0n.h, cb, 0, 0, 0);
        dC = __builtin_amdgcn_mfma_f32_16x16x16f16(aL1a.h, B1n.h, cL1a, 0, 0, 0);
        dD = __builtin_amdgcn_mfma_f32_16x16x16f16(aL1b.h, B1n.h, nBD, 0, 0, 0);
    }

    // prefetch buffers for bodies 1..4: x(2..5), Wc pairs t=0..3
    unsigned xh16[4]; float wM[4], w4b[4];
    #pragma unroll
    for (int u = 0; u < 4; ++u) {
        xh16[u] = h16(xp[2 + u]);
        float2 w = *(const float2*)(ws + 8 * u + 2 * g);
        wM[u] = w.x;  w4b[u] = w.y;
    }

    // body(round m): acts from dA/dD/dC, build B(m+1) lane-locally, issue MFMAs
    auto body = [&](unsigned xh_next, float wMu, float w4u) {
        float hA, h4, hC;
        act3(dA, dD, dC, c0, c4, c1, hA, h4, hC);   // h0(m), {g1:h0u4,g2:h1u4}, h1(m-1)
        acc  = fmaf(hC, wMu, acc);                  // fused MLP head (t = m-1)
        acc4 = fmaf(h4, w4u, acc4);                 // only g2's (h1u4) is used
        unsigned hx0  = h16(hA) | (h16(h4) << 16);
        unsigned hc16 = h16(hC);
        HB2 B0n, B1n;
        B0n.u[0] = isg0 ? lolo(hx0, xh_next) : hx0;  B0n.u[1] = 0u;
        B1n.u[0] = lolo(hx0, hc16);                  B1n.u[1] = hx0 >> 16;
        dA = __builtin_amdgcn_mfma_f32_16x16x16f16(aL0a.h, B0n.h, cL0a, 0, 0, 0);
        f4 nBD = __builtin_amdgcn_mfma_f32_16x16x16f16(aL0b.h, B0n.h, cb, 0, 0, 0);
        dC = __builtin_amdgcn_mfma_f32_16x16x16f16(aL1a.h, B1n.h, cL1a, 0, 0, 0);
        dD = __builtin_amdgcn_mfma_f32_16x16x16f16(aL1b.h, B1n.h, nBD, 0, 0, 0);
    };

    for (int m = 1; m < 513; m += 4) {              // bodies 1..512, blocks of 4
        unsigned xhn[4]; float wMn[4], w4n[4];
        #pragma unroll
        for (int u = 0; u < 4; ++u) {
            xhn[u] = h16(xp[min(m + 5 + u, SEQ - 1)]);
            const int t = min(m + 3 + u, SEQ - 1);
            float2 w = *(const float2*)(ws + 8 * t + 2 * g);
            wMn[u] = w.x;  w4n[u] = w.y;
        }
        #pragma unroll
        for (int u = 0; u < 4; ++u) body(xh16[u], wM[u], w4b[u]);
        #pragma unroll
        for (int u = 0; u < 4; ++u) { xh16[u] = xhn[u]; wM[u] = wMn[u]; w4b[u] = w4n[u]; }
    }

    // reduce: element e partials live on lanes e, e+16, e+32(+u4), e+48
    float accT = acc + (isg2 ? acc4 : 0.f);
    float t0 = bpermf(e15 << 2, accT);
    float t1 = bpermf((e15 + 16) << 2, accT);
    float t2 = bpermf((e15 + 32) << 2, accT);
    float t3 = bpermf((e15 + 48) << 2, accT);
    if (lane < 16) out[e] = (t0 + t1) + (t2 + t3) + ws[4096];
}

extern "C" void kernel_launch(void* const* d_in, const int* in_sizes, int n_in,
                              void* d_out, int out_size, void* d_ws, size_t ws_size,
                              hipStream_t stream) {
    const float* x    = (const float*)d_in[0];
    const float* Wih0 = (const float*)d_in[1];
    const float* Whh0 = (const float*)d_in[2];
    const float* bih0 = (const float*)d_in[3];
    const float* bhh0 = (const float*)d_in[4];
    const float* Wih1 = (const float*)d_in[5];
    const float* Whh1 = (const float*)d_in[6];
    const float* bih1 = (const float*)d_in[7];
    const float* bhh1 = (const float*)d_in[8];
    const float* W1   = (const float*)d_in[9];
    const float* b1   = (const float*)d_in[10];
    const float* W2   = (const float*)d_in[11];
    const float* b2   = (const float*)d_in[12];
    float* out = (float*)d_out;
    float* ws  = (float*)d_ws;

    collapse_kernel<<<160, 256, 0, stream>>>(W1, b1, W2, b2, ws);
    lstm_fused_kernel<<<BATCH / 16, 64, 0, stream>>>(x, Wih0, Whh0, bih0, bhh0,
                                                     Wih1, Whh1, bih1, bhh1, ws, out);
}

// Round 3
// 206.044 us; speedup vs baseline: 1.2484x; 1.0319x over previous
//
#include <hip/hip_runtime.h>

#define BATCH 16384
#define SEQ 512

typedef float f4 __attribute__((ext_vector_type(4)));
typedef _Float16 half4 __attribute__((ext_vector_type(4)));

// Activation inputs pre-scaled into the weights:
//   sigmoid rows (i,f,o): x -log2(e)  -> A=exp2(p), sig = 1/(1+A)
//   tanh row (g):         x -2log2(e) -> B=exp2(p), tanh=(1-B)/(1+B)
#define SIGS (-1.44269504088896f)
#define TNHS (-2.88539008177793f)

union HB2 { unsigned int u[2]; half4 h; };

__device__ __forceinline__ float bpermf(int addr, float v) {
    return __int_as_float(__builtin_amdgcn_ds_bpermute(addr, __float_as_int(v)));
}
__device__ __forceinline__ unsigned int h16(float v) {  // fp16 bits (RNE), low half
    return (unsigned int)__builtin_bit_cast(unsigned short, (_Float16)v);
}
// packed f32->f16x2 (RTZ), one instruction
__device__ __forceinline__ unsigned int pk2(float a, float b) {
    return __builtin_bit_cast(unsigned int, __builtin_amdgcn_cvt_pkrtz(a, b));
}
// v_perm_b32 halfword packer: a.lo | b.lo<<16
__device__ __forceinline__ unsigned int lolo(unsigned int a, unsigned int b) {
    return __builtin_amdgcn_perm(b, a, 0x05040100u);
}

// ws layout (per-g contiguous float2 pairs): ws[g*1024 + 2t] = Wc[t*5+g],
// ws[g*1024 + 2t + 1] = Wc[t*5+4]. Wc = W2@W1 (MLP collapses). ws[4096]=cbias.
__global__ __launch_bounds__(256) void collapse_kernel(
    const float* __restrict__ W1, const float* __restrict__ b1,
    const float* __restrict__ W2, const float* __restrict__ b2,
    float* __restrict__ ws)
{
    const int kl = threadIdx.x & 15;
    const int ms = threadIdx.x >> 4;          // 0..15, 32 rows each
    const int k  = blockIdx.x * 16 + kl;      // 160 blocks * 16 = 2560
    const float* w1p = W1 + (size_t)(ms * 32) * 2560 + k;
    const float* w2p = W2 + ms * 32;
    float acc = 0.f;
    #pragma unroll 8
    for (int m = 0; m < 32; ++m) acc = fmaf(w2p[m], w1p[(size_t)m * 2560], acc);
    __shared__ float red[16][17];
    red[ms][kl] = acc;
    __syncthreads();
    if (ms == 0) {
        float s = 0.f;
        #pragma unroll
        for (int r = 0; r < 16; ++r) s += red[r][kl];
        const int t = k / 5, u = k % 5;
        if (u < 4) ws[(u << 10) + 2 * t] = s;
        else {
            ws[2*t + 1] = s;        ws[1024 + 2*t + 1] = s;
            ws[2048 + 2*t + 1] = s; ws[3072 + 2*t + 1] = s;
        }
    }
    if (blockIdx.x == 0) {
        const int t = threadIdx.x;
        float p = fmaf(W2[t], b1[t], W2[t + 256] * b1[t + 256]);
        #pragma unroll
        for (int off = 32; off > 0; off >>= 1) p += __shfl_down(p, off);
        __shared__ float cred[4];
        if ((t & 63) == 0) cred[t >> 6] = p;
        __syncthreads();
        if (t == 0) ws[4096] = cred[0] + cred[1] + cred[2] + cred[3] + b2[0];
    }
}

// Bperm-free MFMA LSTM, latency-split body:
//   [merged input side for 3 chains] -> hA,h4 (shared rcp) -> pack B0 -> L0 MFMAs
//   [chain2 output (full-round slack)] -> hC -> pack B1 -> L1 MFMAs
// K-slot layout (every B half-word produced by the lane that packs it):
//   B0: g0:{h0u0, x}  g1:{h0u1, h0u4}  g2:{h0u2}  g3:{h0u3}
//   B1: g:{h0ug, h1ug, (g1:h0u4 / g2:h1u4)}
// Unused slots hold garbage x structurally-zero A columns (|h|<=1: no Inf).
__global__ __launch_bounds__(64)
__attribute__((amdgpu_waves_per_eu(1, 1)))
void lstm_fused_kernel(
    const float* __restrict__ x,
    const float* __restrict__ Wih0, const float* __restrict__ Whh0,
    const float* __restrict__ bih0, const float* __restrict__ bhh0,
    const float* __restrict__ Wih1, const float* __restrict__ Whh1,
    const float* __restrict__ bih1, const float* __restrict__ bhh1,
    const float* __restrict__ ws, float* __restrict__ out)
{
    const int lane = threadIdx.x;
    const int e15  = lane & 15;
    const int g    = lane >> 4;          // k-block / lane group / cell index
    const int e    = blockIdx.x * 16 + e15;
    const float sc[4] = {SIGS, SIGS, TNHS, SIGS};

    // ---- A fragments (weights, fp16): lane holds A[row=e15][k=4g+j] ----
    HB2 aL0a, aL0b, aL1a, aL1b;
    {
        const int m = e15;
        {   // L0a: row m -> cell u=m>>2, gate gi=m&3; k0=Whh0[.][g], k1: g0->x, g1->h0u4
            const int u = m >> 2, gi = m & 3, gr = gi * 5 + u;
            const float s = sc[gi];
            float w0 = Whh0[gr * 5 + g];
            float w1 = (g == 0) ? Wih0[gr] : (g == 1 ? Whh0[gr * 5 + 4] : 0.f);
            aL0a.u[0] = h16(w0 * s) | (h16(w1 * s) << 16);
            aL0a.u[1] = 0u;
        }
        {   // L0b: rows 4..7 = L0u4 gates, same column map
            float w0 = 0.f, w1 = 0.f, s = 0.f;
            if (m >= 4 && m < 8) {
                const int gi = m - 4, gr = gi * 5 + 4;
                s = sc[gi];
                w0 = Whh0[gr * 5 + g];
                w1 = (g == 0) ? Wih0[gr] : (g == 1 ? Whh0[gr * 5 + 4] : 0.f);
            }
            aL0b.u[0] = h16(w0 * s) | (h16(w1 * s) << 16);
            aL0b.u[1] = 0u;
        }
        {   // L1a: slot0=Wih1[.][g], slot1=Whh1[.][g], slot2: g1->Wih1[.][4], g2->Whh1[.][4]
            const int u = m >> 2, gi = m & 3, gr = gi * 5 + u;
            const float s = sc[gi];
            float w0 = Wih1[gr * 5 + g];
            float w1 = Whh1[gr * 5 + g];
            float w2 = (g == 1) ? Wih1[gr * 5 + 4] : (g == 2 ? Whh1[gr * 5 + 4] : 0.f);
            aL1a.u[0] = h16(w0 * s) | (h16(w1 * s) << 16);
            aL1a.u[1] = h16(w2 * s);
        }
        {   // L1b: rows 8..11 = L1u4 gates, same column map
            float w0 = 0.f, w1 = 0.f, w2 = 0.f, s = 0.f;
            if (m >= 8 && m < 12) {
                const int gi = m - 8, gr = gi * 5 + 4;
                s = sc[gi];
                w0 = Wih1[gr * 5 + g];
                w1 = Whh1[gr * 5 + g];
                w2 = (g == 1) ? Wih1[gr * 5 + 4] : (g == 2 ? Whh1[gr * 5 + 4] : 0.f);
            }
            aL1b.u[0] = h16(w0 * s) | (h16(w1 * s) << 16);
            aL1b.u[1] = h16(w2 * s);
        }
    }
    // ---- C fragments (biases, fp32): lane reg r -> row 4g+r; cb = merged u4 bias ----
    f4 cL0a, cL1a, cb;
    #pragma unroll
    for (int r = 0; r < 4; ++r) {
        cL0a[r] = (bih0[r*5+g] + bhh0[r*5+g]) * sc[r];
        cL1a[r] = (bih1[r*5+g] + bhh1[r*5+g]) * sc[r];
        cb[r]   = (g == 1) ? (bih0[r*5+4] + bhh0[r*5+4]) * sc[r]
                : (g == 2) ? (bih1[r*5+4] + bhh1[r*5+4]) * sc[r] : 0.f;
    }

    const float* xp  = x + (size_t)e * SEQ;
    const float* wsg = ws + (g << 10);
    const bool isg0 = (g == 0), isg2 = (g == 2);
    // per-lane perm selectors for B0: low16 = hx0.lo; high16 = g0 ? xpair.(lo/hi) : hx0.hi
    const unsigned selA = isg0 ? 0x05040100u : 0x03020100u;
    const unsigned selB = isg0 ? 0x07060100u : 0x03020100u;

    float c0 = 0.f, c1 = 0.f, c4 = 0.f, acc = 0.f, acc4 = 0.f;
    f4 dA, dC, dD;

    // ---- prologue: step 0 (L0 real; L1 state forced to zero) ----
    {
        float2 x01 = *(const float2*)xp;
        unsigned xh0 = h16(x01.x), xh1 = h16(x01.y);
        HB2 b0; b0.u[0] = isg0 ? (xh0 << 16) : 0u; b0.u[1] = 0u;  // k1 = x(0)
        dA = __builtin_amdgcn_mfma_f32_16x16x16f16(aL0a.h, b0.h, cL0a, 0, 0, 0);
        f4 dBD = __builtin_amdgcn_mfma_f32_16x16x16f16(aL0b.h, b0.h, cb, 0, 0, 0);
        // 2-chain act on (dA, dBD)
        float A0 = __builtin_amdgcn_exp2f(dA[0]),  F0 = __builtin_amdgcn_exp2f(dA[1]);
        float B0 = __builtin_amdgcn_exp2f(dA[2]),  O0 = __builtin_amdgcn_exp2f(dA[3]);
        float A1 = __builtin_amdgcn_exp2f(dBD[0]), F1 = __builtin_amdgcn_exp2f(dBD[1]);
        float B1 = __builtin_amdgcn_exp2f(dBD[2]), O1 = __builtin_amdgcn_exp2f(dBD[3]);
        float t0 = 1.f + A0, t1 = 1.f + A1;
        float ab0 = fmaf(t0, B0, t0), ab1 = fmaf(t1, B1, t1);
        float D0 = fmaf(ab0, F0, ab0), D1 = fmaf(ab1, F1, ab1);
        float r = __builtin_amdgcn_rcpf(D0 * D1);
        float r0 = r * D1, r1 = r * D0;
        float bm0 = 1.f - B0, bm1 = 1.f - B1;
        float w0 = fmaf(bm0, F0, bm0), w1 = fmaf(bm1, F1, bm1);
        c0 = fmaf(ab0 * r0, c0, w0 * r0);
        c4 = fmaf(ab1 * r1, c4, w1 * r1);
        float Ce0 = __builtin_amdgcn_exp2f(fminf(c0 * TNHS, 17.f));
        float Ce1 = __builtin_amdgcn_exp2f(fminf(c4 * TNHS, 17.f));
        float o0 = 1.f + O0, o1 = 1.f + O1;
        float e0 = fmaf(o0, Ce0, o0), e1 = fmaf(o1, Ce1, o1);
        float rr = __builtin_amdgcn_rcpf(e0 * e1);
        float hA = (1.f - Ce0) * (rr * e1);
        float h4 = (1.f - Ce1) * (rr * e0);
        if (isg2) { h4 = 0.f; c4 = 0.f; }   // h1u4(-1) = 0
        unsigned hx0 = pk2(hA, h4);
        HB2 B0n, B1n;
        B0n.u[0] = isg0 ? lolo(hx0, xh1) : hx0;  B0n.u[1] = 0u;
        dA = __builtin_amdgcn_mfma_f32_16x16x16f16(aL0a.h, B0n.h, cL0a, 0, 0, 0);
        f4 nBD = __builtin_amdgcn_mfma_f32_16x16x16f16(aL0b.h, B0n.h, cb, 0, 0, 0);
        B1n.u[0] = pk2(hA, 0.f);  B1n.u[1] = pk2(h4, 0.f);   // h1(-1) = 0
        dC = __builtin_amdgcn_mfma_f32_16x16x16f16(aL1a.h, B1n.h, cL1a, 0, 0, 0);
        dD = __builtin_amdgcn_mfma_f32_16x16x16f16(aL1b.h, B1n.h, nBD, 0, 0, 0);
    }

    // body(round m): latency-split act, build B(m+1) lane-locally, issue MFMAs
    auto body = [&](unsigned xpair, unsigned sel, float wMu, float w4u) {
        // merged input side: 12 exp2, one 3-way rcp
        float A0 = __builtin_amdgcn_exp2f(dA[0]), F0 = __builtin_amdgcn_exp2f(dA[1]);
        float B0 = __builtin_amdgcn_exp2f(dA[2]), O0 = __builtin_amdgcn_exp2f(dA[3]);
        float A1 = __builtin_amdgcn_exp2f(dD[0]), F1 = __builtin_amdgcn_exp2f(dD[1]);
        float B1 = __builtin_amdgcn_exp2f(dD[2]), O1 = __builtin_amdgcn_exp2f(dD[3]);
        float A2 = __builtin_amdgcn_exp2f(dC[0]), F2 = __builtin_amdgcn_exp2f(dC[1]);
        float B2 = __builtin_amdgcn_exp2f(dC[2]), O2 = __builtin_amdgcn_exp2f(dC[3]);
        float t0 = 1.f + A0, t1 = 1.f + A1, t2 = 1.f + A2;
        float ab0 = fmaf(t0, B0, t0), ab1 = fmaf(t1, B1, t1), ab2 = fmaf(t2, B2, t2);
        float D0 = fmaf(ab0, F0, ab0), D1 = fmaf(ab1, F1, ab1), D2 = fmaf(ab2, F2, ab2);
        float p01 = D0 * D1, p12 = D1 * D2, p02 = D0 * D2;
        float r = __builtin_amdgcn_rcpf(p01 * D2);
        float r0 = r * p12, r1 = r * p02, r2 = r * p01;
        float bm0 = 1.f - B0, bm1 = 1.f - B1, bm2 = 1.f - B2;
        float w0 = fmaf(bm0, F0, bm0), w1 = fmaf(bm1, F1, bm1), w2 = fmaf(bm2, F2, bm2);
        c0 = fmaf(ab0 * r0, c0, w0 * r0);
        c4 = fmaf(ab1 * r1, c4, w1 * r1);
        c1 = fmaf(ab2 * r2, c1, w2 * r2);
        // chains 0&1 output (L0 recurrence-critical): shared rcp
        float Ce0 = __builtin_amdgcn_exp2f(fminf(c0 * TNHS, 17.f));
        float Ce1 = __builtin_amdgcn_exp2f(fminf(c4 * TNHS, 17.f));
        float o0 = 1.f + O0, o1 = 1.f + O1;
        float e0 = fmaf(o0, Ce0, o0), e1 = fmaf(o1, Ce1, o1);
        float rr = __builtin_amdgcn_rcpf(e0 * e1);
        float hA = (1.f - Ce0) * (rr * e1);     // h0u_g (step m)
        float h4 = (1.f - Ce1) * (rr * e0);     // g1: h0u4, g2: h1u4
        unsigned hx0 = pk2(hA, h4);
        HB2 B0n;
        B0n.u[0] = __builtin_amdgcn_perm(xpair, hx0, sel);  B0n.u[1] = 0u;
        f4 nA  = __builtin_amdgcn_mfma_f32_16x16x16f16(aL0a.h, B0n.h, cL0a, 0, 0, 0);
        f4 nBD = __builtin_amdgcn_mfma_f32_16x16x16f16(aL0b.h, B0n.h, cb, 0, 0, 0);
        // chain 2 output (h1u_g, step m-1; full-round slack)
        float Ce2 = __builtin_amdgcn_exp2f(fminf(c1 * TNHS, 17.f));
        float o2 = 1.f + O2;
        float e2 = fmaf(o2, Ce2, o2);
        float hC = (1.f - Ce2) * __builtin_amdgcn_rcpf(e2);
        acc  = fmaf(hC, wMu, acc);              // fused MLP head (t = m-1)
        acc4 = fmaf(h4, w4u, acc4);             // only g2's (h1u4) is used
        HB2 B1n;
        B1n.u[0] = pk2(hA, hC);  B1n.u[1] = pk2(h4, 0.f);
        dC = __builtin_amdgcn_mfma_f32_16x16x16f16(aL1a.h, B1n.h, cL1a, 0, 0, 0);
        dD = __builtin_amdgcn_mfma_f32_16x16x16f16(aL1b.h, B1n.h, nBD, 0, 0, 0);
        dA = nA;
    };

    // prefetch buffers for bodies 1..4: x(2..5) packed, Wc pairs t=0..3
    unsigned xqa, xqb;  float4 wqa, wqb;
    {
        float2 xi0 = *(const float2*)(xp + 2);
        float2 xi1 = *(const float2*)(xp + 4);
        xqa = pk2(xi0.x, xi0.y);  xqb = pk2(xi1.x, xi1.y);
        wqa = *(const float4*)(wsg);
        wqb = *(const float4*)(wsg + 4);
    }
    for (int m = 1; m < 502; m += 4) {          // bodies 1..504, no clamps
        float2 xi0 = *(const float2*)(xp + m + 5);
        float2 xi1 = *(const float2*)(xp + m + 7);
        unsigned nxa = pk2(xi0.x, xi0.y), nxb = pk2(xi1.x, xi1.y);
        float4 nwa = *(const float4*)(wsg + 2 * (m + 3));
        float4 nwb = *(const float4*)(wsg + 2 * (m + 3) + 4);
        body(xqa, selA, wqa.x, wqa.y);
        body(xqa, selB, wqa.z, wqa.w);
        body(xqb, selA, wqb.x, wqb.y);
        body(xqb, selB, wqb.z, wqb.w);
        xqa = nxa; xqb = nxb; wqa = nwa; wqb = nwb;
    }
    {   // block m=505 (bodies 505..508): x prefetch clamped, ws t=508..511
        unsigned nxa = pk2(xp[510], xp[511]);
        unsigned nxb = pk2(xp[511], xp[511]);
        float4 nwa = *(const float4*)(wsg + 2 * 508);
        float4 nwb = *(const float4*)(wsg + 2 * 508 + 4);
        body(xqa, selA, wqa.x, wqa.y);
        body(xqa, selB, wqa.z, wqa.w);
        body(xqb, selA, wqb.x, wqb.y);
        body(xqb, selB, wqb.z, wqb.w);
        xqa = nxa; xqb = nxb; wqa = nwa; wqb = nwb;
    }
    {   // block m=509 (bodies 509..512): no prefetch
        body(xqa, selA, wqa.x, wqa.y);
        body(xqa, selB, wqa.z, wqa.w);
        body(xqb, selA, wqb.x, wqb.y);
        body(xqb, selB, wqb.z, wqb.w);
    }

    // reduce: element e partials live on lanes e, e+16, e+32(+u4), e+48
    float accT = acc + (isg2 ? acc4 : 0.f);
    float t0 = bpermf(e15 << 2, accT);
    float t1 = bpermf((e15 + 16) << 2, accT);
    float t2 = bpermf((e15 + 32) << 2, accT);
    float t3 = bpermf((e15 + 48) << 2, accT);
    if (lane < 16) out[e] = (t0 + t1) + (t2 + t3) + ws[4096];
}

extern "C" void kernel_launch(void* const* d_in, const int* in_sizes, int n_in,
                              void* d_out, int out_size, void* d_ws, size_t ws_size,
                              hipStream_t stream) {
    const float* x    = (const float*)d_in[0];
    const float* Wih0 = (const float*)d_in[1];
    const float* Whh0 = (const float*)d_in[2];
    const float* bih0 = (const float*)d_in[3];
    const float* bhh0 = (const float*)d_in[4];
    const float* Wih1 = (const float*)d_in[5];
    const float* Whh1 = (const float*)d_in[6];
    const float* bih1 = (const float*)d_in[7];
    const float* bhh1 = (const float*)d_in[8];
    const float* W1   = (const float*)d_in[9];
    const float* b1   = (const float*)d_in[10];
    const float* W2   = (const float*)d_in[11];
    const float* b2   = (const float*)d_in[12];
    float* out = (float*)d_out;
    float* ws  = (float*)d_ws;

    collapse_kernel<<<160, 256, 0, stream>>>(W1, b1, W2, b2, ws);
    lstm_fused_kernel<<<BATCH / 16, 64, 0, stream>>>(x, Wih0, Whh0, bih0, bhh0,
                                                     Wih1, Whh1, bih1, bhh1, ws, out);
}

// Round 4
// 200.824 us; speedup vs baseline: 1.2808x; 1.0260x over previous
//
#include <hip/hip_runtime.h>

#define BATCH 16384
#define SEQ 512

typedef float f4 __attribute__((ext_vector_type(4)));
typedef _Float16 half4 __attribute__((ext_vector_type(4)));

// Activation inputs pre-scaled into the weights:
//   sigmoid rows (i,f,o): x -log2(e)  -> A=exp2(p), sig = 1/(1+A)
//   tanh row (g):         x -2log2(e) -> B=exp2(p), tanh=(1-B)/(1+B)
#define SIGS (-1.44269504088896f)
#define TNHS (-2.88539008177793f)
#define NTNH (2.88539008177793f)

union HB2 { unsigned int u[2]; half4 h; };

__device__ __forceinline__ float bpermf(int addr, float v) {
    return __int_as_float(__builtin_amdgcn_ds_bpermute(addr, __float_as_int(v)));
}
__device__ __forceinline__ unsigned int h16(float v) {  // fp16 bits (RNE), low half
    return (unsigned int)__builtin_bit_cast(unsigned short, (_Float16)v);
}
// packed f32->f16x2 (RTZ), one instruction
__device__ __forceinline__ unsigned int pk2(float a, float b) {
    return __builtin_bit_cast(unsigned int, __builtin_amdgcn_cvt_pkrtz(a, b));
}
// v_perm_b32 halfword packer: a.lo | b.lo<<16
__device__ __forceinline__ unsigned int lolo(unsigned int a, unsigned int b) {
    return __builtin_amdgcn_perm(b, a, 0x05040100u);
}

// ws layout (per-g contiguous float2 pairs): ws[g*1024 + 2t] = Wc[t*5+g],
// ws[g*1024 + 2t + 1] = Wc[t*5+4]. Wc = W2@W1 (MLP collapses). ws[4096]=cbias.
__global__ __launch_bounds__(256) void collapse_kernel(
    const float* __restrict__ W1, const float* __restrict__ b1,
    const float* __restrict__ W2, const float* __restrict__ b2,
    float* __restrict__ ws)
{
    const int kl = threadIdx.x & 15;
    const int ms = threadIdx.x >> 4;          // 0..15, 32 rows each
    const int k  = blockIdx.x * 16 + kl;      // 160 blocks * 16 = 2560
    const float* w1p = W1 + (size_t)(ms * 32) * 2560 + k;
    const float* w2p = W2 + ms * 32;
    float acc = 0.f;
    #pragma unroll 8
    for (int m = 0; m < 32; ++m) acc = fmaf(w2p[m], w1p[(size_t)m * 2560], acc);
    __shared__ float red[16][17];
    red[ms][kl] = acc;
    __syncthreads();
    if (ms == 0) {
        float s = 0.f;
        #pragma unroll
        for (int r = 0; r < 16; ++r) s += red[r][kl];
        const int t = k / 5, u = k % 5;
        if (u < 4) ws[(u << 10) + 2 * t] = s;
        else {
            ws[2*t + 1] = s;        ws[1024 + 2*t + 1] = s;
            ws[2048 + 2*t + 1] = s; ws[3072 + 2*t + 1] = s;
        }
    }
    if (blockIdx.x == 0) {
        const int t = threadIdx.x;
        float p = fmaf(W2[t], b1[t], W2[t + 256] * b1[t + 256]);
        #pragma unroll
        for (int off = 32; off > 0; off >>= 1) p += __shfl_down(p, off);
        __shared__ float cred[4];
        if ((t & 63) == 0) cred[t >> 6] = p;
        __syncthreads();
        if (t == 0) ws[4096] = cred[0] + cred[1] + cred[2] + cred[3] + b2[0];
    }
}

// Bperm-free MFMA LSTM, unchained spine:
//   chain1 input = dBD + dD (disjoint-row sum replaces accumulator chaining:
//   aL0b rows 8-15 = 0, aL1b rows 4-7 = 0, biases split cb0/cb1) -> both MFMA
//   pairs independent; dD (spine) issues before dC. Cell state kept TNHS-scaled.
// K-slot layout (every B half-word produced by the lane that packs it):
//   B0: g0:{h0u0, x}  g1:{h0u1, h0u4}  g2:{h0u2}  g3:{h0u3}
//   B1: g:{h0ug, h1ug, (g1:h0u4 / g2:h1u4)}
// Unused slots hold garbage x structurally-zero A columns (|h|<=1: no Inf).
__global__ __launch_bounds__(64)
__attribute__((amdgpu_waves_per_eu(1, 1)))
void lstm_fused_kernel(
    const float* __restrict__ x,
    const float* __restrict__ Wih0, const float* __restrict__ Whh0,
    const float* __restrict__ bih0, const float* __restrict__ bhh0,
    const float* __restrict__ Wih1, const float* __restrict__ Whh1,
    const float* __restrict__ bih1, const float* __restrict__ bhh1,
    const float* __restrict__ ws, float* __restrict__ out)
{
    const int lane = threadIdx.x;
    const int e15  = lane & 15;
    const int g    = lane >> 4;          // k-block / lane group / cell index
    const int e    = blockIdx.x * 16 + e15;
    const float sc[4] = {SIGS, SIGS, TNHS, SIGS};

    // ---- A fragments (weights, fp16): lane holds A[row=e15][k=4g+j] ----
    HB2 aL0a, aL0b, aL1a, aL1b;
    {
        const int m = e15;
        {   // L0a: row m -> cell u=m>>2, gate gi=m&3; k0=Whh0[.][g], k1: g0->x, g1->h0u4
            const int u = m >> 2, gi = m & 3, gr = gi * 5 + u;
            const float s = sc[gi];
            float w0 = Whh0[gr * 5 + g];
            float w1 = (g == 0) ? Wih0[gr] : (g == 1 ? Whh0[gr * 5 + 4] : 0.f);
            aL0a.u[0] = h16(w0 * s) | (h16(w1 * s) << 16);
            aL0a.u[1] = 0u;
        }
        {   // L0b: rows 4..7 = L0u4 gates, same column map (all other rows zero)
            float w0 = 0.f, w1 = 0.f, s = 0.f;
            if (m >= 4 && m < 8) {
                const int gi = m - 4, gr = gi * 5 + 4;
                s = sc[gi];
                w0 = Whh0[gr * 5 + g];
                w1 = (g == 0) ? Wih0[gr] : (g == 1 ? Whh0[gr * 5 + 4] : 0.f);
            }
            aL0b.u[0] = h16(w0 * s) | (h16(w1 * s) << 16);
            aL0b.u[1] = 0u;
        }
        {   // L1a: slot0=Wih1[.][g], slot1=Whh1[.][g], slot2: g1->Wih1[.][4], g2->Whh1[.][4]
            const int u = m >> 2, gi = m & 3, gr = gi * 5 + u;
            const float s = sc[gi];
            float w0 = Wih1[gr * 5 + g];
            float w1 = Whh1[gr * 5 + g];
            float w2 = (g == 1) ? Wih1[gr * 5 + 4] : (g == 2 ? Whh1[gr * 5 + 4] : 0.f);
            aL1a.u[0] = h16(w0 * s) | (h16(w1 * s) << 16);
            aL1a.u[1] = h16(w2 * s);
        }
        {   // L1b: rows 8..11 = L1u4 gates, same column map (all other rows zero)
            float w0 = 0.f, w1 = 0.f, w2 = 0.f, s = 0.f;
            if (m >= 8 && m < 12) {
                const int gi = m - 8, gr = gi * 5 + 4;
                s = sc[gi];
                w0 = Wih1[gr * 5 + g];
                w1 = Whh1[gr * 5 + g];
                w2 = (g == 1) ? Wih1[gr * 5 + 4] : (g == 2 ? Whh1[gr * 5 + 4] : 0.f);
            }
            aL1b.u[0] = h16(w0 * s) | (h16(w1 * s) << 16);
            aL1b.u[1] = h16(w2 * s);
        }
    }
    // ---- C fragments (biases, fp32): lane reg r -> row 4g+r; cb0/cb1 split ----
    f4 cL0a, cL1a, cb0, cb1;
    #pragma unroll
    for (int r = 0; r < 4; ++r) {
        cL0a[r] = (bih0[r*5+g] + bhh0[r*5+g]) * sc[r];
        cL1a[r] = (bih1[r*5+g] + bhh1[r*5+g]) * sc[r];
        cb0[r]  = (g == 1) ? (bih0[r*5+4] + bhh0[r*5+4]) * sc[r] : 0.f;
        cb1[r]  = (g == 2) ? (bih1[r*5+4] + bhh1[r*5+4]) * sc[r] : 0.f;
    }

    const float* xp  = x + (size_t)e * SEQ;
    const float* wsg = ws + (g << 10);
    const bool isg0 = (g == 0), isg2 = (g == 2);
    // per-lane perm selectors for B0: low16 = hx0.lo; high16 = g0 ? xpair.(lo/hi) : hx0.hi
    const unsigned selA = isg0 ? 0x05040100u : 0x03020100u;
    const unsigned selB = isg0 ? 0x07060100u : 0x03020100u;

    float cs0 = 0.f, cs1 = 0.f, cs4 = 0.f, acc = 0.f, acc4 = 0.f;
    f4 dA, dC, dD, dBD;

    // ---- prologue: step 0 (L0 real; L1 state forced to zero) ----
    {
        float2 x01 = *(const float2*)xp;
        unsigned xh0 = h16(x01.x), xh1 = h16(x01.y);
        HB2 b0; b0.u[0] = isg0 ? (xh0 << 16) : 0u; b0.u[1] = 0u;  // k1 = x(0)
        dA  = __builtin_amdgcn_mfma_f32_16x16x16f16(aL0a.h, b0.h, cL0a, 0, 0, 0);
        dBD = __builtin_amdgcn_mfma_f32_16x16x16f16(aL0b.h, b0.h, cb0, 0, 0, 0);
        // 2-chain act (private rcps), TNHS-scaled cell state
        float A0 = __builtin_amdgcn_exp2f(dA[0]),  F0 = __builtin_amdgcn_exp2f(dA[1]);
        float B0 = __builtin_amdgcn_exp2f(dA[2]),  O0 = __builtin_amdgcn_exp2f(dA[3]);
        float A1 = __builtin_amdgcn_exp2f(dBD[0]), F1 = __builtin_amdgcn_exp2f(dBD[1]);
        float B1 = __builtin_amdgcn_exp2f(dBD[2]), O1 = __builtin_amdgcn_exp2f(dBD[3]);
        float t0 = 1.f + A0, t1 = 1.f + A1;
        float ab0 = fmaf(t0, B0, t0), ab1 = fmaf(t1, B1, t1);
        float D0 = fmaf(ab0, F0, ab0), D1 = fmaf(ab1, F1, ab1);
        float r0 = __builtin_amdgcn_rcpf(D0), r1 = __builtin_amdgcn_rcpf(D1);
        float bs0 = fmaf(B0, NTNH, TNHS), bs1 = fmaf(B1, NTNH, TNHS);
        float w0 = fmaf(bs0, F0, bs0), w1 = fmaf(bs1, F1, bs1);
        cs0 = fmaf(ab0, cs0, w0) * r0;
        cs4 = fmaf(ab1, cs4, w1) * r1;
        float Ce0 = __builtin_amdgcn_exp2f(fminf(cs0, 17.f));
        float Ce1 = __builtin_amdgcn_exp2f(fminf(cs4, 17.f));
        float o0 = 1.f + O0, o1 = 1.f + O1;
        float e0 = fmaf(o0, Ce0, o0), e1 = fmaf(o1, Ce1, o1);
        float hA = (1.f - Ce0) * __builtin_amdgcn_rcpf(e0);
        float h4 = (1.f - Ce1) * __builtin_amdgcn_rcpf(e1);
        if (isg2) { h4 = 0.f; cs4 = 0.f; }   // h1u4(-1) = 0
        unsigned hx0 = pk2(hA, h4);
        HB2 B0n, B1n;
        B0n.u[0] = isg0 ? lolo(hx0, xh1) : hx0;  B0n.u[1] = 0u;
        dA  = __builtin_amdgcn_mfma_f32_16x16x16f16(aL0a.h, B0n.h, cL0a, 0, 0, 0);
        dBD = __builtin_amdgcn_mfma_f32_16x16x16f16(aL0b.h, B0n.h, cb0, 0, 0, 0);
        B1n.u[0] = pk2(hA, 0.f);  B1n.u[1] = hx0 >> 16;   // hC(-1) = 0
        dD = __builtin_amdgcn_mfma_f32_16x16x16f16(aL1b.h, B1n.h, cb1, 0, 0, 0);
        dC = __builtin_amdgcn_mfma_f32_16x16x16f16(aL1a.h, B1n.h, cL1a, 0, 0, 0);
    }

    // body(step m): dU = dBD+dD at front, acts, lane-local packs, MFMAs (dD first)
    auto body = [&](unsigned xpair, unsigned sel, float wMu, float w4u) {
        f4 dU;
        #pragma unroll
        for (int r = 0; r < 4; ++r) dU[r] = dBD[r] + dD[r];
        // merged input side: 12 exp2, one 3-way rcp
        float A0 = __builtin_amdgcn_exp2f(dA[0]), F0 = __builtin_amdgcn_exp2f(dA[1]);
        float B0 = __builtin_amdgcn_exp2f(dA[2]), O0 = __builtin_amdgcn_exp2f(dA[3]);
        float A1 = __builtin_amdgcn_exp2f(dU[0]), F1 = __builtin_amdgcn_exp2f(dU[1]);
        float B1 = __builtin_amdgcn_exp2f(dU[2]), O1 = __builtin_amdgcn_exp2f(dU[3]);
        float A2 = __builtin_amdgcn_exp2f(dC[0]), F2 = __builtin_amdgcn_exp2f(dC[1]);
        float B2 = __builtin_amdgcn_exp2f(dC[2]), O2 = __builtin_amdgcn_exp2f(dC[3]);
        float t0 = 1.f + A0, t1 = 1.f + A1, t2 = 1.f + A2;
        float ab0 = fmaf(t0, B0, t0), ab1 = fmaf(t1, B1, t1), ab2 = fmaf(t2, B2, t2);
        float D0 = fmaf(ab0, F0, ab0), D1 = fmaf(ab1, F1, ab1), D2 = fmaf(ab2, F2, ab2);
        float p01 = D0 * D1, p12 = D1 * D2, p02 = D0 * D2;
        float r = __builtin_amdgcn_rcpf(p01 * D2);
        float r0 = r * p12, r1 = r * p02, r2 = r * p01;
        float bs0 = fmaf(B0, NTNH, TNHS), bs1 = fmaf(B1, NTNH, TNHS), bs2 = fmaf(B2, NTNH, TNHS);
        float w0 = fmaf(bs0, F0, bs0), w1 = fmaf(bs1, F1, bs1), w2 = fmaf(bs2, F2, bs2);
        cs0 = fmaf(ab0, cs0, w0) * r0;      // TNHS-scaled c; post-rcp = 1 mul
        cs4 = fmaf(ab1, cs4, w1) * r1;
        cs1 = fmaf(ab2, cs1, w2) * r2;
        // chains 0&1 output (feed B0): shared rcp
        float Ce0 = __builtin_amdgcn_exp2f(fminf(cs0, 17.f));
        float Ce1 = __builtin_amdgcn_exp2f(fminf(cs4, 17.f));
        float o0 = 1.f + O0, o1 = 1.f + O1;
        float e0 = fmaf(o0, Ce0, o0), e1 = fmaf(o1, Ce1, o1);
        float rr = __builtin_amdgcn_rcpf(e0 * e1);
        float hA = (1.f - Ce0) * (rr * e1);     // h0u_g (step m)
        float h4 = (1.f - Ce1) * (rr * e0);     // g1: h0u4, g2: h1u4
        unsigned hx0 = pk2(hA, h4);
        HB2 B0n;
        B0n.u[0] = __builtin_amdgcn_perm(xpair, hx0, sel);  B0n.u[1] = 0u;
        f4 nA  = __builtin_amdgcn_mfma_f32_16x16x16f16(aL0a.h, B0n.h, cL0a, 0, 0, 0);
        f4 nBD = __builtin_amdgcn_mfma_f32_16x16x16f16(aL0b.h, B0n.h, cb0, 0, 0, 0);
        // chain 2 output (h1u_g, step m-1)
        float Ce2 = __builtin_amdgcn_exp2f(fminf(cs1, 17.f));
        float o2 = 1.f + O2;
        float e2 = fmaf(o2, Ce2, o2);
        float hC = (1.f - Ce2) * __builtin_amdgcn_rcpf(e2);
        acc  = fmaf(hC, wMu, acc);              // fused MLP head (t = m-1)
        acc4 = fmaf(h4, w4u, acc4);             // only g2's (h1u4) is used
        HB2 B1n;
        B1n.u[0] = pk2(hA, hC);  B1n.u[1] = hx0 >> 16;
        dD = __builtin_amdgcn_mfma_f32_16x16x16f16(aL1b.h, B1n.h, cb1, 0, 0, 0);  // spine first
        dC = __builtin_amdgcn_mfma_f32_16x16x16f16(aL1a.h, B1n.h, cL1a, 0, 0, 0);
        dA = nA;  dBD = nBD;
    };

    // prefetch buffers for bodies 1..4: x(2..5) packed, Wc pairs t=0..3
    unsigned xqa, xqb;  float4 wqa, wqb;
    {
        float2 xi0 = *(const float2*)(xp + 2);
        float2 xi1 = *(const float2*)(xp + 4);
        xqa = pk2(xi0.x, xi0.y);  xqb = pk2(xi1.x, xi1.y);
        wqa = *(const float4*)(wsg);
        wqb = *(const float4*)(wsg + 4);
    }
    for (int m = 1; m < 502; m += 4) {          // bodies 1..504, no clamps
        float2 xi0 = *(const float2*)(xp + m + 5);
        float2 xi1 = *(const float2*)(xp + m + 7);
        unsigned nxa = pk2(xi0.x, xi0.y), nxb = pk2(xi1.x, xi1.y);
        float4 nwa = *(const float4*)(wsg + 2 * (m + 3));
        float4 nwb = *(const float4*)(wsg + 2 * (m + 3) + 4);
        body(xqa, selA, wqa.x, wqa.y);
        body(xqa, selB, wqa.z, wqa.w);
        body(xqb, selA, wqb.x, wqb.y);
        body(xqb, selB, wqb.z, wqb.w);
        xqa = nxa; xqb = nxb; wqa = nwa; wqb = nwb;
    }
    {   // block m=505 (bodies 505..508): x prefetch clamped, ws t=508..511
        unsigned nxa = pk2(xp[510], xp[511]);
        unsigned nxb = pk2(xp[511], xp[511]);
        float4 nwa = *(const float4*)(wsg + 2 * 508);
        float4 nwb = *(const float4*)(wsg + 2 * 508 + 4);
        body(xqa, selA, wqa.x, wqa.y);
        body(xqa, selB, wqa.z, wqa.w);
        body(xqb, selA, wqb.x, wqb.y);
        body(xqb, selB, wqb.z, wqb.w);
        xqa = nxa; xqb = nxb; wqa = nwa; wqb = nwb;
    }
    {   // block m=509 (bodies 509..512): no prefetch
        body(xqa, selA, wqa.x, wqa.y);
        body(xqa, selB, wqa.z, wqa.w);
        body(xqb, selA, wqb.x, wqb.y);
        body(xqb, selB, wqb.z, wqb.w);
    }

    // reduce: element e partials live on lanes e, e+16, e+32(+u4), e+48
    float accT = acc + (isg2 ? acc4 : 0.f);
    float t0 = bpermf(e15 << 2, accT);
    float t1 = bpermf((e15 + 16) << 2, accT);
    float t2 = bpermf((e15 + 32) << 2, accT);
    float t3 = bpermf((e15 + 48) << 2, accT);
    if (lane < 16) out[e] = (t0 + t1) + (t2 + t3) + ws[4096];
}

extern "C" void kernel_launch(void* const* d_in, const int* in_sizes, int n_in,
                              void* d_out, int out_size, void* d_ws, size_t ws_size,
                              hipStream_t stream) {
    const float* x    = (const float*)d_in[0];
    const float* Wih0 = (const float*)d_in[1];
    const float* Whh0 = (const float*)d_in[2];
    const float* bih0 = (const float*)d_in[3];
    const float* bhh0 = (const float*)d_in[4];
    const float* Wih1 = (const float*)d_in[5];
    const float* Whh1 = (const float*)d_in[6];
    const float* bih1 = (const float*)d_in[7];
    const float* bhh1 = (const float*)d_in[8];
    const float* W1   = (const float*)d_in[9];
    const float* b1   = (const float*)d_in[10];
    const float* W2   = (const float*)d_in[11];
    const float* b2   = (const float*)d_in[12];
    float* out = (float*)d_out;
    float* ws  = (float*)d_ws;

    collapse_kernel<<<160, 256, 0, stream>>>(W1, b1, W2, b2, ws);
    lstm_fused_kernel<<<BATCH / 16, 64, 0, stream>>>(x, Wih0, Whh0, bih0, bhh0,
                                                     Wih1, Whh1, bih1, bhh1, ws, out);
}

// Round 5
// 192.359 us; speedup vs baseline: 1.3372x; 1.0440x over previous
//
#include <hip/hip_runtime.h>

#define BATCH 16384
#define SEQ 512

typedef float f4 __attribute__((ext_vector_type(4)));
typedef _Float16 half4 __attribute__((ext_vector_type(4)));
typedef _Float16 half8 __attribute__((ext_vector_type(8)));

// Activation inputs pre-scaled into the weights:
//   sigmoid rows (i,f,o): x -log2(e)  -> A=exp2(p), sig = 1/(1+A)
//   tanh row (g):         x -2log2(e) -> B=exp2(p), tanh=(1-B)/(1+B)
#define SIGS (-1.44269504088896f)
#define TNHS (-2.88539008177793f)
#define NTNH (2.88539008177793f)

union HB2 { unsigned int u[2]; half4 h; };
union HB4 { unsigned int u[4]; half8 h; };

__device__ __forceinline__ float bpermf(int addr, float v) {
    return __int_as_float(__builtin_amdgcn_ds_bpermute(addr, __float_as_int(v)));
}
__device__ __forceinline__ unsigned int h16(float v) {  // fp16 bits (RNE), low half
    return (unsigned int)__builtin_bit_cast(unsigned short, (_Float16)v);
}
// packed f32->f16x2 (RTZ), one instruction
__device__ __forceinline__ unsigned int pk2(float a, float b) {
    return __builtin_bit_cast(unsigned int, __builtin_amdgcn_cvt_pkrtz(a, b));
}
// v_perm_b32 halfword packer: a.lo | b.lo<<16
__device__ __forceinline__ unsigned int lolo(unsigned int a, unsigned int b) {
    return __builtin_amdgcn_perm(b, a, 0x05040100u);
}

// ws layout (per-g contiguous float2 pairs): ws[g*1024 + 2t] = Wc[t*5+g],
// ws[g*1024 + 2t + 1] = Wc[t*5+4]. Wc = W2@W1 (MLP collapses). ws[4096]=cbias.
__global__ __launch_bounds__(256) void collapse_kernel(
    const float* __restrict__ W1, const float* __restrict__ b1,
    const float* __restrict__ W2, const float* __restrict__ b2,
    float* __restrict__ ws)
{
    const int kl = threadIdx.x & 15;
    const int ms = threadIdx.x >> 4;          // 0..15, 32 rows each
    const int k  = blockIdx.x * 16 + kl;      // 160 blocks * 16 = 2560
    const float* w1p = W1 + (size_t)(ms * 32) * 2560 + k;
    const float* w2p = W2 + ms * 32;
    float acc = 0.f;
    #pragma unroll 8
    for (int m = 0; m < 32; ++m) acc = fmaf(w2p[m], w1p[(size_t)m * 2560], acc);
    __shared__ float red[16][17];
    red[ms][kl] = acc;
    __syncthreads();
    if (ms == 0) {
        float s = 0.f;
        #pragma unroll
        for (int r = 0; r < 16; ++r) s += red[r][kl];
        const int t = k / 5, u = k % 5;
        if (u < 4) ws[(u << 10) + 2 * t] = s;
        else {
            ws[2*t + 1] = s;        ws[1024 + 2*t + 1] = s;
            ws[2048 + 2*t + 1] = s; ws[3072 + 2*t + 1] = s;
        }
    }
    if (blockIdx.x == 0) {
        const int t = threadIdx.x;
        float p = fmaf(W2[t], b1[t], W2[t + 256] * b1[t + 256]);
        #pragma unroll
        for (int off = 32; off > 0; off >>= 1) p += __shfl_down(p, off);
        __shared__ float cred[4];
        if ((t & 63) == 0) cred[t >> 6] = p;
        __syncthreads();
        if (t == 0) ws[4096] = cred[0] + cred[1] + cred[2] + cred[3] + b2[0];
    }
}

// Bperm-free MFMA LSTM, 3-MFMA body:
//   dA  = 16x16x16(aL0a, B0)              -- L0 cells 0..3, issued mid-body
//   dU  = 16x16x32(aU,  {B0,0,B1lo,B1hi}) -- L0u4 (rows 4-7, k-slots j0-1) and
//         L1u4 (rows 8-11, k-slots j4-6) in ONE mfma: dU direct, no add.
//   dC  = 16x16x16(aL1a, B1)              -- L1 cells 0..3, slack 1 step
// Input rcps: {chain0*chain1 shared, chain2 private} -- spine never waits on D2.
// Chain2 output computed BEFORE chains 0&1 so post-h4 tail = packs + 3 issues.
// K-slot layout (every B half-word produced by the lane that packs it):
//   B0: g0:{h0u0, x}  g1:{h0u1, h0u4}  g2:{h0u2}  g3:{h0u3}
//   B1: g:{h0ug, h1ug, (g1:h0u4 / g2:h1u4)}
// Unused slots hold garbage x structurally-zero A columns (|h|<=1: no Inf).
__global__ __launch_bounds__(64)
__attribute__((amdgpu_waves_per_eu(1, 1)))
void lstm_fused_kernel(
    const float* __restrict__ x,
    const float* __restrict__ Wih0, const float* __restrict__ Whh0,
    const float* __restrict__ bih0, const float* __restrict__ bhh0,
    const float* __restrict__ Wih1, const float* __restrict__ Whh1,
    const float* __restrict__ bih1, const float* __restrict__ bhh1,
    const float* __restrict__ ws, float* __restrict__ out)
{
    const int lane = threadIdx.x;
    const int e15  = lane & 15;
    const int g    = lane >> 4;          // k-block / lane group / cell index
    const int e    = blockIdx.x * 16 + e15;
    const float sc[4] = {SIGS, SIGS, TNHS, SIGS};

    // ---- A fragments (weights, fp16) ----
    HB2 aL0a, aL1a;
    HB4 aU;
    {
        const int m = e15;
        {   // L0a: row m -> cell u=m>>2, gate gi=m&3; k0=Whh0[.][g], k1: g0->x, g1->h0u4
            const int u = m >> 2, gi = m & 3, gr = gi * 5 + u;
            const float s = sc[gi];
            float w0 = Whh0[gr * 5 + g];
            float w1 = (g == 0) ? Wih0[gr] : (g == 1 ? Whh0[gr * 5 + 4] : 0.f);
            aL0a.u[0] = h16(w0 * s) | (h16(w1 * s) << 16);
            aL0a.u[1] = 0u;
        }
        {   // L1a: slot0=Wih1[.][g], slot1=Whh1[.][g], slot2: g1->Wih1[.][4], g2->Whh1[.][4]
            const int u = m >> 2, gi = m & 3, gr = gi * 5 + u;
            const float s = sc[gi];
            float w0 = Wih1[gr * 5 + g];
            float w1 = Whh1[gr * 5 + g];
            float w2 = (g == 1) ? Wih1[gr * 5 + 4] : (g == 2 ? Whh1[gr * 5 + 4] : 0.f);
            aL1a.u[0] = h16(w0 * s) | (h16(w1 * s) << 16);
            aL1a.u[1] = h16(w2 * s);
        }
        {   // aU j0-1: L0b (rows 4..7 = L0u4 gates, B0 column map)
            float w0 = 0.f, w1 = 0.f, s = 0.f;
            if (m >= 4 && m < 8) {
                const int gi = m - 4, gr = gi * 5 + 4;
                s = sc[gi];
                w0 = Whh0[gr * 5 + g];
                w1 = (g == 0) ? Wih0[gr] : (g == 1 ? Whh0[gr * 5 + 4] : 0.f);
            }
            aU.u[0] = h16(w0 * s) | (h16(w1 * s) << 16);
            aU.u[1] = 0u;
        }
        {   // aU j4-6: L1b (rows 8..11 = L1u4 gates, B1 column map)
            float w0 = 0.f, w1 = 0.f, w2 = 0.f, s = 0.f;
            if (m >= 8 && m < 12) {
                const int gi = m - 8, gr = gi * 5 + 4;
                s = sc[gi];
                w0 = Wih1[gr * 5 + g];
                w1 = Whh1[gr * 5 + g];
                w2 = (g == 1) ? Wih1[gr * 5 + 4] : (g == 2 ? Whh1[gr * 5 + 4] : 0.f);
            }
            aU.u[2] = h16(w0 * s) | (h16(w1 * s) << 16);
            aU.u[3] = h16(w2 * s);
        }
    }
    // ---- C fragments (biases, fp32): lane reg r -> row 4g+r; cbm merged u4 bias ----
    f4 cL0a, cL1a, cbm;
    #pragma unroll
    for (int r = 0; r < 4; ++r) {
        cL0a[r] = (bih0[r*5+g] + bhh0[r*5+g]) * sc[r];
        cL1a[r] = (bih1[r*5+g] + bhh1[r*5+g]) * sc[r];
        cbm[r]  = (g == 1) ? (bih0[r*5+4] + bhh0[r*5+4]) * sc[r]
                : (g == 2) ? (bih1[r*5+4] + bhh1[r*5+4]) * sc[r] : 0.f;
    }

    const float* xp  = x + (size_t)e * SEQ;
    const float* wsg = ws + (g << 10);
    const bool isg0 = (g == 0), isg2 = (g == 2);
    // per-lane perm selectors for B0: low16 = hx0.lo; high16 = g0 ? xpair.(lo/hi) : hx0.hi
    const unsigned selA = isg0 ? 0x05040100u : 0x03020100u;
    const unsigned selB = isg0 ? 0x07060100u : 0x03020100u;

    float cs0 = 0.f, cs1 = 0.f, cs4 = 0.f, acc = 0.f, acc4 = 0.f;
    f4 dA, dC, dU;

    // ---- prologue: step 0 (L0 real; L1 state forced to zero) ----
    {
        float2 x01 = *(const float2*)xp;
        unsigned xh0 = h16(x01.x), xh1 = h16(x01.y);
        HB2 b0; b0.u[0] = isg0 ? (xh0 << 16) : 0u; b0.u[1] = 0u;  // k1 = x(0)
        dA = __builtin_amdgcn_mfma_f32_16x16x16f16(aL0a.h, b0.h, cL0a, 0, 0, 0);
        HB4 bu0; bu0.u[0] = b0.u[0]; bu0.u[1] = bu0.u[2] = bu0.u[3] = 0u;
        dU = __builtin_amdgcn_mfma_f32_16x16x32_f16(aU.h, bu0.h, cbm, 0, 0, 0);
        // 2-chain act (private rcps), TNHS-scaled cell state
        float A0 = __builtin_amdgcn_exp2f(dA[0]), F0 = __builtin_amdgcn_exp2f(dA[1]);
        float B0 = __builtin_amdgcn_exp2f(dA[2]), O0 = __builtin_amdgcn_exp2f(dA[3]);
        float A1 = __builtin_amdgcn_exp2f(dU[0]), F1 = __builtin_amdgcn_exp2f(dU[1]);
        float B1 = __builtin_amdgcn_exp2f(dU[2]), O1 = __builtin_amdgcn_exp2f(dU[3]);
        float t0 = 1.f + A0, t1 = 1.f + A1;
        float ab0 = fmaf(t0, B0, t0), ab1 = fmaf(t1, B1, t1);
        float D0 = fmaf(ab0, F0, ab0), D1 = fmaf(ab1, F1, ab1);
        float r0 = __builtin_amdgcn_rcpf(D0), r1 = __builtin_amdgcn_rcpf(D1);
        float bs0 = fmaf(B0, NTNH, TNHS), bs1 = fmaf(B1, NTNH, TNHS);
        float w0 = fmaf(bs0, F0, bs0), w1 = fmaf(bs1, F1, bs1);
        cs0 = fmaf(ab0, cs0, w0) * r0;
        cs4 = fmaf(ab1, cs4, w1) * r1;
        float Ce0 = __builtin_amdgcn_exp2f(fminf(cs0, 17.f));
        float Ce1 = __builtin_amdgcn_exp2f(fminf(cs4, 17.f));
        float o0 = 1.f + O0, o1 = 1.f + O1;
        float e0 = fmaf(o0, Ce0, o0), e1 = fmaf(o1, Ce1, o1);
        float hA = (1.f - Ce0) * __builtin_amdgcn_rcpf(e0);
        float h4 = (1.f - Ce1) * __builtin_amdgcn_rcpf(e1);
        if (isg2) { h4 = 0.f; cs4 = 0.f; }   // h1u4(-1) = 0
        unsigned hx0 = pk2(hA, h4);
        HB2 B0n, B1n;
        B0n.u[0] = isg0 ? lolo(hx0, xh1) : hx0;  B0n.u[1] = 0u;
        dA = __builtin_amdgcn_mfma_f32_16x16x16f16(aL0a.h, B0n.h, cL0a, 0, 0, 0);
        B1n.u[0] = pk2(hA, 0.f);  B1n.u[1] = hx0 >> 16;   // hC(-1) = 0
        HB4 BU; BU.u[0] = B0n.u[0]; BU.u[1] = 0u; BU.u[2] = B1n.u[0]; BU.u[3] = B1n.u[1];
        dU = __builtin_amdgcn_mfma_f32_16x16x32_f16(aU.h, BU.h, cbm, 0, 0, 0);
        dC = __builtin_amdgcn_mfma_f32_16x16x16f16(aL1a.h, B1n.h, cL1a, 0, 0, 0);
    }

    // body(step m): input exps, {01-shared, 2-private} rcps, chain2 output FIRST,
    // then spine chains 0&1, packs, MFMAs in order nA -> dU(spine) -> dC(slack)
    auto body = [&](unsigned xpair, unsigned sel, float wMu, float w4u) {
        float A0 = __builtin_amdgcn_exp2f(dA[0]), F0 = __builtin_amdgcn_exp2f(dA[1]);
        float B0 = __builtin_amdgcn_exp2f(dA[2]), O0 = __builtin_amdgcn_exp2f(dA[3]);
        float A1 = __builtin_amdgcn_exp2f(dU[0]), F1 = __builtin_amdgcn_exp2f(dU[1]);
        float B1 = __builtin_amdgcn_exp2f(dU[2]), O1 = __builtin_amdgcn_exp2f(dU[3]);
        float A2 = __builtin_amdgcn_exp2f(dC[0]), F2 = __builtin_amdgcn_exp2f(dC[1]);
        float B2 = __builtin_amdgcn_exp2f(dC[2]), O2 = __builtin_amdgcn_exp2f(dC[3]);
        float t0 = 1.f + A0, t1 = 1.f + A1, t2 = 1.f + A2;
        float ab0 = fmaf(t0, B0, t0), ab1 = fmaf(t1, B1, t1), ab2 = fmaf(t2, B2, t2);
        float D0 = fmaf(ab0, F0, ab0), D1 = fmaf(ab1, F1, ab1), D2 = fmaf(ab2, F2, ab2);
        float r01 = __builtin_amdgcn_rcpf(D0 * D1);   // spine pair, no D2 coupling
        float r0 = r01 * D1, r1 = r01 * D0;
        float r2 = __builtin_amdgcn_rcpf(D2);         // slack chain private
        float bs0 = fmaf(B0, NTNH, TNHS), bs1 = fmaf(B1, NTNH, TNHS), bs2 = fmaf(B2, NTNH, TNHS);
        float w0 = fmaf(bs0, F0, bs0), w1 = fmaf(bs1, F1, bs1), w2 = fmaf(bs2, F2, bs2);
        cs0 = fmaf(ab0, cs0, w0) * r0;      // TNHS-scaled c; post-rcp = 1 mul
        cs4 = fmaf(ab1, cs4, w1) * r1;
        cs1 = fmaf(ab2, cs1, w2) * r2;
        // chain 2 output FIRST (h1u_g, step m-1): hC ready before spine tail
        float Ce2 = __builtin_amdgcn_exp2f(fminf(cs1, 17.f));
        float o2 = 1.f + O2;
        float e2 = fmaf(o2, Ce2, o2);
        float hC = (1.f - Ce2) * __builtin_amdgcn_rcpf(e2);
        acc  = fmaf(hC, wMu, acc);              // fused MLP head (t = m-1)
        // chains 0&1 output (spine): shared rcp
        float Ce0 = __builtin_amdgcn_exp2f(fminf(cs0, 17.f));
        float Ce1 = __builtin_amdgcn_exp2f(fminf(cs4, 17.f));
        float o0 = 1.f + O0, o1 = 1.f + O1;
        float e0 = fmaf(o0, Ce0, o0), e1 = fmaf(o1, Ce1, o1);
        float rr = __builtin_amdgcn_rcpf(e0 * e1);
        float hA = (1.f - Ce0) * (rr * e1);     // h0u_g (step m)
        float h4 = (1.f - Ce1) * (rr * e0);     // g1: h0u4, g2: h1u4
        acc4 = fmaf(h4, w4u, acc4);             // only g2's (h1u4) is used
        unsigned hx0  = pk2(hA, h4);
        unsigned b1lo = pk2(hA, hC);
        unsigned b1hi = hx0 >> 16;
        HB2 B0n;
        B0n.u[0] = __builtin_amdgcn_perm(xpair, hx0, sel);  B0n.u[1] = 0u;
        dA = __builtin_amdgcn_mfma_f32_16x16x16f16(aL0a.h, B0n.h, cL0a, 0, 0, 0);
        HB4 BU; BU.u[0] = B0n.u[0]; BU.u[1] = 0u; BU.u[2] = b1lo; BU.u[3] = b1hi;
        dU = __builtin_amdgcn_mfma_f32_16x16x32_f16(aU.h, BU.h, cbm, 0, 0, 0);  // spine
        HB2 B1n; B1n.u[0] = b1lo; B1n.u[1] = b1hi;
        dC = __builtin_amdgcn_mfma_f32_16x16x16f16(aL1a.h, B1n.h, cL1a, 0, 0, 0);
    };

    // prefetch buffers for bodies 1..4: x(2..5) packed, Wc pairs t=0..3
    unsigned xqa, xqb;  float4 wqa, wqb;
    {
        float2 xi0 = *(const float2*)(xp + 2);
        float2 xi1 = *(const float2*)(xp + 4);
        xqa = pk2(xi0.x, xi0.y);  xqb = pk2(xi1.x, xi1.y);
        wqa = *(const float4*)(wsg);
        wqb = *(const float4*)(wsg + 4);
    }
    for (int m = 1; m < 502; m += 4) {          // bodies 1..504, no clamps
        float2 xi0 = *(const float2*)(xp + m + 5);
        float2 xi1 = *(const float2*)(xp + m + 7);
        unsigned nxa = pk2(xi0.x, xi0.y), nxb = pk2(xi1.x, xi1.y);
        float4 nwa = *(const float4*)(wsg + 2 * (m + 3));
        float4 nwb = *(const float4*)(wsg + 2 * (m + 3) + 4);
        body(xqa, selA, wqa.x, wqa.y);
        body(xqa, selB, wqa.z, wqa.w);
        body(xqb, selA, wqb.x, wqb.y);
        body(xqb, selB, wqb.z, wqb.w);
        xqa = nxa; xqb = nxb; wqa = nwa; wqb = nwb;
    }
    {   // block m=505 (bodies 505..508): x prefetch clamped, ws t=508..511
        unsigned nxa = pk2(xp[510], xp[511]);
        unsigned nxb = pk2(xp[511], xp[511]);
        float4 nwa = *(const float4*)(wsg + 2 * 508);
        float4 nwb = *(const float4*)(wsg + 2 * 508 + 4);
        body(xqa, selA, wqa.x, wqa.y);
        body(xqa, selB, wqa.z, wqa.w);
        body(xqb, selA, wqb.x, wqb.y);
        body(xqb, selB, wqb.z, wqb.w);
        xqa = nxa; xqb = nxb; wqa = nwa; wqb = nwb;
    }
    {   // block m=509 (bodies 509..512): no prefetch
        body(xqa, selA, wqa.x, wqa.y);
        body(xqa, selB, wqa.z, wqa.w);
        body(xqb, selA, wqb.x, wqb.y);
        body(xqb, selB, wqb.z, wqb.w);
    }

    // reduce: element e partials live on lanes e, e+16, e+32(+u4), e+48
    float accT = acc + (isg2 ? acc4 : 0.f);
    float t0 = bpermf(e15 << 2, accT);
    float t1 = bpermf((e15 + 16) << 2, accT);
    float t2 = bpermf((e15 + 32) << 2, accT);
    float t3 = bpermf((e15 + 48) << 2, accT);
    if (lane < 16) out[e] = (t0 + t1) + (t2 + t3) + ws[4096];
}

extern "C" void kernel_launch(void* const* d_in, const int* in_sizes, int n_in,
                              void* d_out, int out_size, void* d_ws, size_t ws_size,
                              hipStream_t stream) {
    const float* x    = (const float*)d_in[0];
    const float* Wih0 = (const float*)d_in[1];
    const float* Whh0 = (const float*)d_in[2];
    const float* bih0 = (const float*)d_in[3];
    const float* bhh0 = (const float*)d_in[4];
    const float* Wih1 = (const float*)d_in[5];
    const float* Whh1 = (const float*)d_in[6];
    const float* bih1 = (const float*)d_in[7];
    const float* bhh1 = (const float*)d_in[8];
    const float* W1   = (const float*)d_in[9];
    const float* b1   = (const float*)d_in[10];
    const float* W2   = (const float*)d_in[11];
    const float* b2   = (const float*)d_in[12];
    float* out = (float*)d_out;
    float* ws  = (float*)d_ws;

    collapse_kernel<<<160, 256, 0, stream>>>(W1, b1, W2, b2, ws);
    lstm_fused_kernel<<<BATCH / 16, 64, 0, stream>>>(x, Wih0, Whh0, bih0, bhh0,
                                                     Wih1, Whh1, bih1, bhh1, ws, out);
}